// Round 1
// baseline (79.737 us; speedup 1.0000x reference)
//
#include <hip/hip_runtime.h>
#include <math.h>

// SH up to lmax=3 with input normalization. f32 in (N,3), f32 out (N,16).
// Memory-bound: ~243 MB traffic -> ~39 us roofline at 6.3 TB/s.

__global__ __launch_bounds__(256) void sh_lmax3_kernel(
    const float* __restrict__ ev, float* __restrict__ out, int n) {

    const float sqrt3  = 1.7320508075688772f;
    const float sqrt5  = 2.2360679774997896f;
    const float sqrt15 = 3.8729833462074170f;
    const float c30    = 1.0801234497346435f;  // sqrt(42)/6
    const float c31    = 2.6457513110645907f;  // sqrt(7)
    const float c32    = 1.6201851746019651f;  // sqrt(168)/8
    const float c33    = 1.3228756555322954f;  // 0.5*sqrt(7)

    int idx    = blockIdx.x * blockDim.x + threadIdx.x;
    int stride = gridDim.x * blockDim.x;

    for (int i = idx; i < n; i += stride) {
        float x = ev[3 * i + 0];
        float y = ev[3 * i + 1];
        float z = ev[3 * i + 2];

        float s  = x * x + y * y + z * z;
        float rn = 1.0f / fmaxf(sqrtf(s), 1e-12f);
        x *= rn; y *= rn; z *= rn;

        float y2   = y * y;
        float x2z2 = x * x + z * z;

        float sh20 = sqrt15 * x * z;
        float sh21 = sqrt15 * x * y;
        float sh22 = sqrt5 * (y2 - 0.5f * x2z2);
        float sh23 = sqrt15 * y * z;
        float sh24 = 0.5f * sqrt15 * (z * z - x * x);

        float sh30 = c30 * (sh20 * z + sh24 * x);
        float sh31 = c31 * sh20 * y;
        float sh32 = c32 * (4.0f * y2 - x2z2) * x;
        float sh33 = c33 * y * (2.0f * y2 - 3.0f * x2z2);
        float sh34 = c32 * z * (4.0f * y2 - x2z2);
        float sh35 = c31 * sh24 * y;
        float sh36 = c30 * (sh24 * z - sh20 * x);

        float4* o4 = reinterpret_cast<float4*>(out + 16ll * i);
        o4[0] = make_float4(1.0f, sqrt3 * x, sqrt3 * y, sqrt3 * z);
        o4[1] = make_float4(sh20, sh21, sh22, sh23);
        o4[2] = make_float4(sh24, sh30, sh31, sh32);
        o4[3] = make_float4(sh33, sh34, sh35, sh36);
    }
}

extern "C" void kernel_launch(void* const* d_in, const int* in_sizes, int n_in,
                              void* d_out, int out_size, void* d_ws, size_t ws_size,
                              hipStream_t stream) {
    const float* ev = (const float*)d_in[0];
    float* out = (float*)d_out;
    int n = in_sizes[0] / 3;  // in_sizes[0] is flat element count (N*3)

    const int block = 256;
    int grid = (n + block - 1) / block;
    if (grid > 2048) grid = 2048;  // grid-stride; 2048 blocks saturates 256 CUs

    sh_lmax3_kernel<<<grid, block, 0, stream>>>(ev, out, n);
}

// Round 2
// 40.389 us; speedup vs baseline: 1.9742x; 1.9742x over previous
//
#include <hip/hip_runtime.h>
#include <math.h>

// SH lmax=3 with normalization. f32 (N,3) -> f32 (N,16).
// LDS-staged output so global stores are fully coalesced float4 (no partial-line RMW).

#define TILE 256
#define PAD  17   // 17 floats/edge in LDS: gcd(17,32)=1 -> conflict-free b32 access

__global__ __launch_bounds__(256) void sh_lmax3_kernel(
    const float* __restrict__ ev, float* __restrict__ out, int n) {

    __shared__ float so[TILE * PAD];  // 17,408 B

    const float sqrt3  = 1.7320508075688772f;
    const float sqrt5  = 2.2360679774997896f;
    const float sqrt15 = 3.8729833462074170f;
    const float c30    = 1.0801234497346435f;  // sqrt(42)/6
    const float c31    = 2.6457513110645907f;  // sqrt(7)
    const float c32    = 1.6201851746019651f;  // sqrt(168)/8
    const float c33    = 1.3228756555322954f;  // 0.5*sqrt(7)

    const int t     = threadIdx.x;
    const int tile  = blockIdx.x;
    const int e0    = tile * TILE;
    const int e     = e0 + t;

    float x = 0.f, y = 0.f, z = 1.f;
    if (e < n) {
        x = ev[3 * e + 0];
        y = ev[3 * e + 1];
        z = ev[3 * e + 2];
    }

    float s  = x * x + y * y + z * z;
    float rn = 1.0f / fmaxf(sqrtf(s), 1e-12f);
    x *= rn; y *= rn; z *= rn;

    float y2   = y * y;
    float x2z2 = x * x + z * z;

    float sh20 = sqrt15 * x * z;
    float sh21 = sqrt15 * x * y;
    float sh22 = sqrt5 * (y2 - 0.5f * x2z2);
    float sh23 = sqrt15 * y * z;
    float sh24 = 0.5f * sqrt15 * (z * z - x * x);

    float sh30 = c30 * (sh20 * z + sh24 * x);
    float sh31 = c31 * sh20 * y;
    float sh32 = c32 * (4.0f * y2 - x2z2) * x;
    float sh33 = c33 * y * (2.0f * y2 - 3.0f * x2z2);
    float sh34 = c32 * z * (4.0f * y2 - x2z2);
    float sh35 = c31 * sh24 * y;
    float sh36 = c30 * (sh24 * z - sh20 * x);

    float* row = &so[t * PAD];
    row[0]  = 1.0f;
    row[1]  = sqrt3 * x;
    row[2]  = sqrt3 * y;
    row[3]  = sqrt3 * z;
    row[4]  = sh20;
    row[5]  = sh21;
    row[6]  = sh22;
    row[7]  = sh23;
    row[8]  = sh24;
    row[9]  = sh30;
    row[10] = sh31;
    row[11] = sh32;
    row[12] = sh33;
    row[13] = sh34;
    row[14] = sh35;
    row[15] = sh36;

    __syncthreads();

    // Coalesced writeout: this block's output tile is TILE*16 contiguous floats
    // = TILE*4 float4s. Thread t writes float4 #t, #t+256, #t+512, #t+768.
    const int remaining = n - e0;
    const int valid_f4  = (remaining >= TILE ? TILE : remaining) * 4;
    float4* otile = reinterpret_cast<float4*>(out + (long long)e0 * 16);

#pragma unroll
    for (int j = 0; j < 4; ++j) {
        int f = t + TILE * j;
        if (f < valid_f4) {
            int ee = f >> 2;
            int q  = f & 3;
            const float* r = &so[ee * PAD + q * 4];
            otile[f] = make_float4(r[0], r[1], r[2], r[3]);
        }
    }
}

extern "C" void kernel_launch(void* const* d_in, const int* in_sizes, int n_in,
                              void* d_out, int out_size, void* d_ws, size_t ws_size,
                              hipStream_t stream) {
    const float* ev = (const float*)d_in[0];
    float* out = (float*)d_out;
    int n = in_sizes[0] / 3;

    int grid = (n + TILE - 1) / TILE;  // 12500 for N=3.2M
    sh_lmax3_kernel<<<grid, TILE, 0, stream>>>(ev, out, n);
}